// Round 2
// baseline (2493.217 us; speedup 1.0000x reference)
//
#include <hip/hip_runtime.h>
#include <hip/hip_bf16.h>
#include <math.h>

// ---------------------------------------------------------------------------
// out = (A @ D^T) * softplus(A @ R^T + rad_b) + bias
//   A = input [8192,4096] f32, R = rad_w [4096,4096] f32,
//   D = dir_loc * (kappa/(kappa+4095)) rowwise, kappa = softplus(dir_conc_raw)
//
// No fp32 MFMA on CDNA4 -> emulate fp32 GEMM with 2-term bf16 split (hi+lo),
// 3 MFMA terms per product (hh + hl + lh), ~1e-5 relative accuracy.
// Fused dual-GEMM: both GEMMs share A fragments; epilogue fused in-register.
// Structure: m97-proven 128x128 tile, BK=32, 4 waves, global_load_lds(16B),
// single-buffered 2-barrier K-loop.
//
// LDS XOR-swizzle (NEW this round): [128][32] bf16 rows are 64B -> fragment
// ds_read_b128 phases (16 lanes, same 16B chunk, rows 0..15) hit only 2 bank
// quads = 8-way conflict (m98: 1.7e7 conflicts on this geometry). Fix per
// rule #21 (both-sides-or-neither with global_load_lds): LDS dest stays
// linear, each staging lane FETCHES global chunk (tid&3)^((r0>>1)&3) so data
// lands pre-swizzled, reads XOR the chunk index the same way. (chunk,row&1)
// then covers all 8 bank quads exactly 2x per phase -> 2-way = free (m136).
// Fragment row bases are multiples of 16 so the read XOR term is the
// per-lane constant ((lane&15)>>1)&3.
//
// ws layout (bytes): A_hi 0 | A_lo 64M | R_hi 128M | R_lo 160M | D_hi 192M
//                    | D_lo 224M | scale 256M   (total ~256.02 MB)
// ---------------------------------------------------------------------------

typedef __bf16 bf16x8 __attribute__((ext_vector_type(8)));
typedef float  f32x4  __attribute__((ext_vector_type(4)));
typedef unsigned short u16;
typedef u16   u16x4 __attribute__((ext_vector_type(4)));
typedef float f4    __attribute__((ext_vector_type(4)));

#define BDIM 8192
#define IDIM 4096
#define ODIM 4096
#define BM 128
#define BN 128
#define BK 32

__device__ __forceinline__ u16 f2bf(float x){ __bf16 h=(__bf16)x; return __builtin_bit_cast(u16,h); }
__device__ __forceinline__ float bf2f(u16 u){ return (float)__builtin_bit_cast(__bf16,u); }

// --- prep: scale[o] = kappa/(kappa+IDIM-1), kappa = softplus(raw[o]) ---
__global__ void k_scale(const float* __restrict__ raw, float* __restrict__ scale){
  int o = blockIdx.x*256 + threadIdx.x;
  if(o < ODIM){
    float x = raw[o];
    float k = (x > 20.f) ? x : log1pf(expf(x));
    scale[o] = k / (k + (float)(IDIM-1));
  }
}

// --- prep: split fp32 -> bf16 hi + bf16 lo (residual), vectorized x4 ---
__global__ void k_split(const f4* __restrict__ src, u16x4* __restrict__ hi,
                        u16x4* __restrict__ lo, int n4){
  int i = blockIdx.x*blockDim.x + threadIdx.x;
  int stride = gridDim.x*blockDim.x;
  for(; i<n4; i+=stride){
    f4 v = src[i];
    u16x4 h, l;
    #pragma unroll
    for(int j=0;j<4;++j){
      float x = v[j];
      u16 hb = f2bf(x);
      h[j] = hb;
      l[j] = f2bf(x - bf2f(hb));
    }
    hi[i]=h; lo[i]=l;
  }
}

// --- prep: same, with per-row scale (direction matrix) ---
__global__ void k_split_dir(const f4* __restrict__ src, const float* __restrict__ scale,
                            u16x4* __restrict__ hi, u16x4* __restrict__ lo, int n4){
  int i = blockIdx.x*blockDim.x + threadIdx.x;
  int stride = gridDim.x*blockDim.x;
  for(; i<n4; i+=stride){
    float s = scale[i>>10];          // 1024 f4-chunks per 4096-elem row
    f4 v = src[i];
    u16x4 h, l;
    #pragma unroll
    for(int j=0;j<4;++j){
      float x = v[j]*s;
      u16 hb = f2bf(x);
      h[j] = hb;
      l[j] = f2bf(x - bf2f(hb));
    }
    hi[i]=h; lo[i]=l;
  }
}

__device__ __forceinline__ void async16(const u16* g, u16* l){
  __builtin_amdgcn_global_load_lds((const __attribute__((address_space(1))) void*)g,
                                   (__attribute__((address_space(3))) void*)l, 16, 0, 0);
}

// --- fused dual split-GEMM + epilogue ---
__global__ __launch_bounds__(256,2) void k_gemm(
    const u16* __restrict__ Ah, const u16* __restrict__ Al,
    const u16* __restrict__ Rh, const u16* __restrict__ Rl,
    const u16* __restrict__ Dh, const u16* __restrict__ Dl,
    const float* __restrict__ rad_b, const float* __restrict__ bias,
    float* __restrict__ out)
{
  __shared__ __align__(16) u16 smem[6*BM*BK];   // 6 tiles x 8KB = 48 KB

  const int tid  = threadIdx.x;
  const int lane = tid & 63;
  const int wid  = tid >> 6;
  const int wr = wid >> 1, wc = wid & 1;        // wave quadrant in 128x128

  // bijective XCD swizzle (2048 blocks % 8 == 0)
  const int bid = blockIdx.x;
  const int swz = (bid & 7) * (2048/8) + (bid >> 3);
  const int bm = swz >> 5;                      // 0..63
  const int bn = swz & 31;                      // 0..31

  // staging: thread covers tile elements e0=tid and e1=tid+256 (16B each);
  // LDS dest stays LINEAR (slot tid*8 == row r0=tid>>2, chunk tid&3 of
  // [128][32]); the GLOBAL fetch column is the XOR-swizzled chunk so data
  // lands pre-swizzled (rule #21). (r0+64)>>1 keeps the same XOR (64 even).
  const int r0   = tid >> 2;
  const int cxor = (r0 >> 1) & 3;
  const int c0   = ((tid & 3) ^ cxor) * 8;
  const size_t arow = (size_t)(bm*BM + r0)*IDIM + c0;
  const size_t brow = (size_t)(bn*BN + r0)*IDIM + c0;
  const u16* g[6] = { Ah + arow, Al + arow, Rh + brow, Rl + brow, Dh + brow, Dl + brow };
  u16* ld0 = smem + tid*8;

  // MFMA fragment reads (elements): row = quad*64 + (lane&15) + mi*16,
  // chunk = (lane>>4) ^ ((row>>1)&3). Row bases are multiples of 16 so the
  // XOR term is the per-lane constant ((lane&15)>>1)&3; mi adds 512 elems.
  const int lr   = lane & 15;
  const int fxor = (lr >> 1) & 3;
  const int aoff = (wr*64 + lr)*BK + (((lane >> 4) ^ fxor))*8;
  const int boff = (wc*64 + lr)*BK + (((lane >> 4) ^ fxor))*8;

  f32x4 accR[4][4] = {};   // radius GEMM accumulators
  f32x4 accD[4][4] = {};   // direction GEMM accumulators

  for(int kt=0; kt<IDIM/BK; ++kt){
    const int ko = kt*BK;
    #pragma unroll
    for(int t=0;t<6;++t){
      const u16* gp = g[t] + ko;
      async16(gp,           ld0 + t*4096);          // rows 0..63
      async16(gp + 64*IDIM, ld0 + t*4096 + 2048);   // rows 64..127
    }
    __syncthreads();   // compiler drains vmcnt before s_barrier

    bf16x8 ah[4], al[4], b0[4], b1[4];
    #pragma unroll
    for(int mi=0;mi<4;++mi){
      ah[mi] = *(const bf16x8*)(smem +        aoff + mi*512);
      al[mi] = *(const bf16x8*)(smem + 4096 + aoff + mi*512);
    }
    // ---- radius GEMM: acc += Ah*Rh + Ah*Rl + Al*Rh ----
    #pragma unroll
    for(int ni=0;ni<4;++ni){
      b0[ni] = *(const bf16x8*)(smem +  8192 + boff + ni*512);
      b1[ni] = *(const bf16x8*)(smem + 12288 + boff + ni*512);
    }
    #pragma unroll
    for(int mi=0;mi<4;++mi)
      #pragma unroll
      for(int ni=0;ni<4;++ni){
        accR[mi][ni] = __builtin_amdgcn_mfma_f32_16x16x32_bf16(ah[mi], b0[ni], accR[mi][ni], 0,0,0);
        accR[mi][ni] = __builtin_amdgcn_mfma_f32_16x16x32_bf16(ah[mi], b1[ni], accR[mi][ni], 0,0,0);
        accR[mi][ni] = __builtin_amdgcn_mfma_f32_16x16x32_bf16(al[mi], b0[ni], accR[mi][ni], 0,0,0);
      }
    // ---- direction GEMM ----
    #pragma unroll
    for(int ni=0;ni<4;++ni){
      b0[ni] = *(const bf16x8*)(smem + 16384 + boff + ni*512);
      b1[ni] = *(const bf16x8*)(smem + 20480 + boff + ni*512);
    }
    #pragma unroll
    for(int mi=0;mi<4;++mi)
      #pragma unroll
      for(int ni=0;ni<4;++ni){
        accD[mi][ni] = __builtin_amdgcn_mfma_f32_16x16x32_bf16(ah[mi], b0[ni], accD[mi][ni], 0,0,0);
        accD[mi][ni] = __builtin_amdgcn_mfma_f32_16x16x32_bf16(ah[mi], b1[ni], accD[mi][ni], 0,0,0);
        accD[mi][ni] = __builtin_amdgcn_mfma_f32_16x16x32_bf16(al[mi], b0[ni], accD[mi][ni], 0,0,0);
      }
    __syncthreads();
  }

  // epilogue: C/D layout col=lane&15, row=(lane>>4)*4+j  [m89-verified]
  const int orow0 = bm*BM + wr*64 + (lane>>4)*4;
  const int ocol0 = bn*BN + wc*64 + (lane & 15);
  #pragma unroll
  for(int ni=0;ni<4;++ni){
    const int col = ocol0 + ni*16;
    const float rb = rad_b[col];
    const float bs = bias[col];
    #pragma unroll
    for(int mi=0;mi<4;++mi){
      const int row = orow0 + mi*16;
      #pragma unroll
      for(int j=0;j<4;++j){
        float s  = accR[mi][ni][j] + rb;
        float sp = (s > 20.f) ? s : log1pf(expf(s));   // softplus
        out[(size_t)(row+j)*ODIM + col] = accD[mi][ni][j]*sp + bs;
      }
    }
  }
}

extern "C" void kernel_launch(void* const* d_in, const int* in_sizes, int n_in,
                              void* d_out, int out_size, void* d_ws, size_t ws_size,
                              hipStream_t stream){
  (void)in_sizes; (void)n_in; (void)out_size; (void)ws_size;
  const float* inp  = (const float*)d_in[0];  // [8192,4096]
  const float* dirl = (const float*)d_in[1];  // [4096,4096]
  const float* draw = (const float*)d_in[2];  // [4096]
  const float* radw = (const float*)d_in[3];  // [4096,4096]
  const float* radb = (const float*)d_in[4];  // [4096]
  const float* bias = (const float*)d_in[5];  // [4096]
  float* out = (float*)d_out;

  char* ws = (char*)d_ws;                     // needs ~256.02 MB
  u16* Ah = (u16*)(ws);
  u16* Al = (u16*)(ws +  67108864L);
  u16* Rh = (u16*)(ws + 134217728L);
  u16* Rl = (u16*)(ws + 167772160L);
  u16* Dh = (u16*)(ws + 201326592L);
  u16* Dl = (u16*)(ws + 234881024L);
  float* scale = (float*)(ws + 268435456L);

  k_scale<<<dim3(ODIM/256), dim3(256), 0, stream>>>(draw, scale);

  const int n4A = BDIM*IDIM/4;   // 8388608
  const int n4W = ODIM*IDIM/4;   // 4194304
  k_split<<<dim3(2048), dim3(256), 0, stream>>>((const f4*)inp,  (u16x4*)Ah, (u16x4*)Al, n4A);
  k_split<<<dim3(2048), dim3(256), 0, stream>>>((const f4*)radw, (u16x4*)Rh, (u16x4*)Rl, n4W);
  k_split_dir<<<dim3(2048), dim3(256), 0, stream>>>((const f4*)dirl, scale, (u16x4*)Dh, (u16x4*)Dl, n4W);

  k_gemm<<<dim3((BDIM/BM)*(ODIM/BN)), dim3(256), 0, stream>>>(
      Ah, Al, Rh, Rl, Dh, Dl, radb, bias, out);
}

// Round 8
// 1876.428 us; speedup vs baseline: 1.3287x; 1.3287x over previous
//
#include <hip/hip_runtime.h>
#include <hip/hip_bf16.h>
#include <math.h>

// ---------------------------------------------------------------------------
// out = (A @ D^T) * softplus(A @ R^T + rad_b) + bias
// fp32 GEMM emulated via 2-term bf16 split (hh + hl + lh), fused dual-GEMM.
//
// R8 == R3 (never benched: acquisition timeouts R3-R7). Audited 4x.
// Escape the 2-barrier drain ceiling (R2: MfmaUtil 34%, == m97 structural
// stall). T3+T4 counted-vmcnt pipeline (m218: counted vs drain0 +38-73%):
//   - 256x128 tile, 8 waves (per-wave 64x64 accR+accD — IDENTICAL fragment
//     geometry + XOR swizzle to the R2-verified kernel)
//   - double-buffered LDS 2x64KB = 128 KB, BK=32
//   - exactly 8 global_load_lds per tile per wave -> vmcnt(8) waits for
//     current tile while next tile's 8 stay in flight across the barrier
//   - raw s_barrier + sched_barrier(0) region pins (rule #18); NO
//     __syncthreads in the K-loop (it drains vmcnt(0) = the R2 stall)
//   - s_setprio(1) around MFMA clusters (T5; pays once phases exist)
// Iter: vmcnt(8); barrier; [ds_read + MFMA]; lgkmcnt(0); barrier; STAGE(t+2).
// Invariant at iter t top: outstanding = tiles t,t+1 (<=16); vmcnt(8) ->
// tile t landed (per-wave); barrier -> landed for ALL waves.
//
// ws: A_hi 0 | A_lo 64M | R_hi 128M | R_lo 160M | D_hi 192M | D_lo 224M
//     | scale 256M
// ---------------------------------------------------------------------------

typedef __bf16 bf16x8 __attribute__((ext_vector_type(8)));
typedef float  f32x4  __attribute__((ext_vector_type(4)));
typedef unsigned short u16;
typedef u16   u16x4 __attribute__((ext_vector_type(4)));
typedef float f4    __attribute__((ext_vector_type(4)));

#define BDIM 8192
#define IDIM 4096
#define ODIM 4096
#define BM 256
#define BN 128
#define BK 32
#define NKT (IDIM/BK)   // 128

__device__ __forceinline__ u16 f2bf(float x){ __bf16 h=(__bf16)x; return __builtin_bit_cast(u16,h); }
__device__ __forceinline__ float bf2f(u16 u){ return (float)__builtin_bit_cast(__bf16,u); }

__global__ void k_scale(const float* __restrict__ raw, float* __restrict__ scale){
  int o = blockIdx.x*256 + threadIdx.x;
  if(o < ODIM){
    float x = raw[o];
    float k = (x > 20.f) ? x : log1pf(expf(x));
    scale[o] = k / (k + (float)(IDIM-1));
  }
}

__global__ void k_split(const f4* __restrict__ src, u16x4* __restrict__ hi,
                        u16x4* __restrict__ lo, int n4){
  int i = blockIdx.x*blockDim.x + threadIdx.x;
  int stride = gridDim.x*blockDim.x;
  for(; i<n4; i+=stride){
    f4 v = src[i];
    u16x4 h, l;
    #pragma unroll
    for(int j=0;j<4;++j){
      float x = v[j];
      u16 hb = f2bf(x);
      h[j] = hb;
      l[j] = f2bf(x - bf2f(hb));
    }
    hi[i]=h; lo[i]=l;
  }
}

__global__ void k_split_dir(const f4* __restrict__ src, const float* __restrict__ scale,
                            u16x4* __restrict__ hi, u16x4* __restrict__ lo, int n4){
  int i = blockIdx.x*blockDim.x + threadIdx.x;
  int stride = gridDim.x*blockDim.x;
  for(; i<n4; i+=stride){
    float s = scale[i>>10];
    f4 v = src[i];
    u16x4 h, l;
    #pragma unroll
    for(int j=0;j<4;++j){
      float x = v[j]*s;
      u16 hb = f2bf(x);
      h[j] = hb;
      l[j] = f2bf(x - bf2f(hb));
    }
    hi[i]=h; lo[i]=l;
  }
}

__device__ __forceinline__ void async16(const u16* g, u16* l){
  __builtin_amdgcn_global_load_lds((const __attribute__((address_space(1))) void*)g,
                                   (__attribute__((address_space(3))) void*)l, 16, 0, 0);
}

// LDS per buffer (u16 elems): Ah[256][32]@0, Al@8192, Rh[128][32]@16384,
// Rl@20480, Dh@24576, Dl@28672. Buffer stride 32768 elems (64 KB).
__global__ __launch_bounds__(512,2) void k_gemm(
    const u16* __restrict__ Ah, const u16* __restrict__ Al,
    const u16* __restrict__ Rh, const u16* __restrict__ Rl,
    const u16* __restrict__ Dh, const u16* __restrict__ Dl,
    const float* __restrict__ rad_b, const float* __restrict__ bias,
    float* __restrict__ out)
{
  __shared__ __align__(16) u16 smem[2*32768];   // 128 KB

  const int tid  = threadIdx.x;
  const int lane = tid & 63;
  const int wid  = tid >> 6;                    // 0..7
  const int wr = wid >> 1, wc = wid & 1;        // 4M x 2N wave grid

  // bijective XCD swizzle (1024 blocks % 8 == 0)
  const int bid = blockIdx.x;
  const int swz = (bid & 7)*128 + (bid >> 3);
  const int bm = swz >> 5;                      // 0..31  (256-row panels)
  const int bn = swz & 31;                      // 0..31  (128-col panels)

  // staging: 512 thr x 16B = one [128][32] tile per instruction; A needs 2.
  // LDS dest linear; GLOBAL fetch chunk XOR-swizzled (rule #21; R2-verified,
  // 0 bank conflicts). (r0+128)>>1 keeps same XOR (128 even).
  const int r0   = tid >> 2;                    // 0..127
  const int cxor = (r0 >> 1) & 3;
  const int c0   = ((tid & 3) ^ cxor) * 8;
  const size_t arow = (size_t)(bm*BM + r0)*IDIM + c0;
  const size_t brow = (size_t)(bn*BN + r0)*IDIM + c0;
  const u16* gAh = Ah + arow;  const u16* gAl = Al + arow;
  const u16* gRh = Rh + brow;  const u16* gRl = Rl + brow;
  const u16* gDh = Dh + brow;  const u16* gDl = Dl + brow;
  u16* dst = smem + tid*8;

  // fragment reads (R2-verified): row base multiples of 16 -> XOR term is
  // the per-lane constant ((lane&15)>>1)&3
  const int lr   = lane & 15;
  const int koff = (((lane >> 4) ^ ((lr >> 1) & 3))) * 8;
  const int aoff = (wr*64 + lr)*BK + koff;
  const int boff = (wc*64 + lr)*BK + koff;

  f32x4 accR[4][4] = {};
  f32x4 accD[4][4] = {};

#define STAGE(BUF, KT) { \
    const int _ko = (KT)*BK; \
    u16* _d = dst + (BUF)*32768; \
    async16(gAh + _ko,            _d);         \
    async16(gAh + 128*IDIM + _ko, _d + 4096);  \
    async16(gAl + _ko,            _d + 8192);  \
    async16(gAl + 128*IDIM + _ko, _d + 12288); \
    async16(gRh + _ko,            _d + 16384); \
    async16(gRl + _ko,            _d + 20480); \
    async16(gDh + _ko,            _d + 24576); \
    async16(gDl + _ko,            _d + 28672); \
  }

#define COMPUTE(BUF) { \
    const u16* sb = smem + (BUF)*32768; \
    bf16x8 ah[4], al[4], bh[4], bl[4]; \
    _Pragma("unroll") for(int mi=0;mi<4;++mi){ \
      ah[mi] = *(const bf16x8*)(sb +        aoff + mi*512); \
      al[mi] = *(const bf16x8*)(sb + 8192 + aoff + mi*512); } \
    _Pragma("unroll") for(int ni=0;ni<4;++ni){ \
      bh[ni] = *(const bf16x8*)(sb + 16384 + boff + ni*512); \
      bl[ni] = *(const bf16x8*)(sb + 20480 + boff + ni*512); } \
    __builtin_amdgcn_s_setprio(1); \
    _Pragma("unroll") for(int mi=0;mi<4;++mi) \
      _Pragma("unroll") for(int ni=0;ni<4;++ni){ \
        accR[mi][ni] = __builtin_amdgcn_mfma_f32_16x16x32_bf16(ah[mi], bh[ni], accR[mi][ni],0,0,0); \
        accR[mi][ni] = __builtin_amdgcn_mfma_f32_16x16x32_bf16(ah[mi], bl[ni], accR[mi][ni],0,0,0); \
        accR[mi][ni] = __builtin_amdgcn_mfma_f32_16x16x32_bf16(al[mi], bh[ni], accR[mi][ni],0,0,0); } \
    __builtin_amdgcn_s_setprio(0); \
    _Pragma("unroll") for(int ni=0;ni<4;++ni){ \
      bh[ni] = *(const bf16x8*)(sb + 24576 + boff + ni*512); \
      bl[ni] = *(const bf16x8*)(sb + 28672 + boff + ni*512); } \
    __builtin_amdgcn_s_setprio(1); \
    _Pragma("unroll") for(int mi=0;mi<4;++mi) \
      _Pragma("unroll") for(int ni=0;ni<4;++ni){ \
        accD[mi][ni] = __builtin_amdgcn_mfma_f32_16x16x32_bf16(ah[mi], bh[ni], accD[mi][ni],0,0,0); \
        accD[mi][ni] = __builtin_amdgcn_mfma_f32_16x16x32_bf16(ah[mi], bl[ni], accD[mi][ni],0,0,0); \
        accD[mi][ni] = __builtin_amdgcn_mfma_f32_16x16x32_bf16(al[mi], bh[ni], accD[mi][ni],0,0,0); } \
    __builtin_amdgcn_s_setprio(0); \
  }

// one K-iteration: counted vmcnt BEFORE barrier (loads for next tile stay in
// flight); raw s_barrier; sched_barrier(0) pins region boundaries (rule #18)
#define K_ITER(BUF, VM, DOSTAGE, NEXTK) { \
    asm volatile("s_waitcnt vmcnt(" VM ")" ::: "memory"); \
    __builtin_amdgcn_s_barrier(); \
    __builtin_amdgcn_sched_barrier(0); \
    COMPUTE(BUF); \
    asm volatile("s_waitcnt lgkmcnt(0)" ::: "memory"); \
    __builtin_amdgcn_sched_barrier(0); \
    __builtin_amdgcn_s_barrier(); \
    if (DOSTAGE) { STAGE(BUF, NEXTK) } \
    __builtin_amdgcn_sched_barrier(0); \
  }

  STAGE(0, 0)
  STAGE(1, 1)
  #pragma unroll 1
  for(int t=0; t<NKT-2; t+=2){          // iters 0..125, staging tiles 2..127
    K_ITER(0, "8", true, t+2)
    K_ITER(1, "8", true, t+3)
  }
  K_ITER(0, "8", false, 0)              // iter 126 (tile 127's 8 in flight)
  K_ITER(1, "0", false, 0)              // iter 127 (drain)

#undef K_ITER
#undef COMPUTE
#undef STAGE

  // epilogue: C/D layout col=lane&15, row=(lane>>4)*4+j (R2-verified)
  const int orow0 = bm*BM + wr*64 + (lane>>4)*4;
  const int ocol0 = bn*BN + wc*64 + (lane & 15);
  #pragma unroll
  for(int ni=0;ni<4;++ni){
    const int col = ocol0 + ni*16;
    const float rb = rad_b[col];
    const float bs = bias[col];
    #pragma unroll
    for(int mi=0;mi<4;++mi){
      const int row = orow0 + mi*16;
      #pragma unroll
      for(int j=0;j<4;++j){
        float s  = accR[mi][ni][j] + rb;
        float sp = (s > 20.f) ? s : log1pf(expf(s));
        out[(size_t)(row+j)*ODIM + col] = accD[mi][ni][j]*sp + bs;
      }
    }
  }
}

extern "C" void kernel_launch(void* const* d_in, const int* in_sizes, int n_in,
                              void* d_out, int out_size, void* d_ws, size_t ws_size,
                              hipStream_t stream){
  (void)in_sizes; (void)n_in; (void)out_size; (void)ws_size;
  const float* inp  = (const float*)d_in[0];  // [8192,4096]
  const float* dirl = (const float*)d_in[1];  // [4096,4096]
  const float* draw = (const float*)d_in[2];  // [4096]
  const float* radw = (const float*)d_in[3];  // [4096,4096]
  const float* radb = (const float*)d_in[4];  // [4096]
  const float* bias = (const float*)d_in[5];  // [4096]
  float* out = (float*)d_out;

  char* ws = (char*)d_ws;
  u16* Ah = (u16*)(ws);
  u16* Al = (u16*)(ws +  67108864L);
  u16* Rh = (u16*)(ws + 134217728L);
  u16* Rl = (u16*)(ws + 167772160L);
  u16* Dh = (u16*)(ws + 201326592L);
  u16* Dl = (u16*)(ws + 234881024L);
  float* scale = (float*)(ws + 268435456L);

  k_scale<<<dim3(ODIM/256), dim3(256), 0, stream>>>(draw, scale);

  const int n4A = BDIM*IDIM/4;
  const int n4W = ODIM*IDIM/4;
  k_split<<<dim3(2048), dim3(256), 0, stream>>>((const f4*)inp,  (u16x4*)Ah, (u16x4*)Al, n4A);
  k_split<<<dim3(2048), dim3(256), 0, stream>>>((const f4*)radw, (u16x4*)Rh, (u16x4*)Rl, n4W);
  k_split_dir<<<dim3(2048), dim3(256), 0, stream>>>((const f4*)dirl, scale, (u16x4*)Dh, (u16x4*)Dl, n4W);

  k_gemm<<<dim3((BDIM/BM)*(ODIM/BN)), dim3(512), 0, stream>>>(
      Ah, Al, Rh, Rl, Dh, Dl, radb, bias, out);
}

// Round 9
// 1814.925 us; speedup vs baseline: 1.3737x; 1.0339x over previous
//
#include <hip/hip_runtime.h>
#include <hip/hip_bf16.h>
#include <math.h>

// ---------------------------------------------------------------------------
// out = (A @ D^T) * softplus(A @ R^T + rad_b) + bias
// fp32 GEMM emulated via 2-term bf16 split (hh + hl + lh), fused dual-GEMM.
//
// R9: 4-phase interleave (m201 8-phase port) on top of R8's counted-vmcnt
// pipeline (R8: 1717us, MfmaUtil 43.5% -- monolithic COMPUTE leaves ~4300
// cyc/iter of ds_read->MFMA serialization; m196: fine interleave is the
// lever, T2/T5 only pay once phases exist).
//   - per K-tile: 4 phases x 24 MFMA (accR ni01 | accR ni23 | accD ni01 |
//     accD ni23), each {ds_read; partial stage; BAR; lgkm0; prio1 MFMA
//     prio0; BAR}
//   - staging spread by LDS-region retirement (race-free, no extra bufs):
//     A (4 loads) in P2 (A fully read in P1); R (2) in P3 (read P1+P2);
//     D (2) after P4 (read P3+P4)
//   - vmcnt ledger in P4: vmcnt(6) before P4 post-barrier = t+1 landed
//     (FIFO: 6 newest = t+2's A+R issued so far). Prologue vmcnt(8);
//     tile126 vmcnt(0) drains t127. Never 0 in steady state.
//   - geometry/swizzle/epilogue IDENTICAL to R8 (verified: 0 conflicts,
//     absmax 3.05e-5)
// ws: A_hi 0 | A_lo 64M | R_hi 128M | R_lo 160M | D_hi 192M | D_lo 224M
//     | scale 256M
// ---------------------------------------------------------------------------

typedef __bf16 bf16x8 __attribute__((ext_vector_type(8)));
typedef float  f32x4  __attribute__((ext_vector_type(4)));
typedef unsigned short u16;
typedef u16   u16x4 __attribute__((ext_vector_type(4)));
typedef float f4    __attribute__((ext_vector_type(4)));

#define BDIM 8192
#define IDIM 4096
#define ODIM 4096
#define BM 256
#define BN 128
#define BK 32
#define NKT (IDIM/BK)   // 128

__device__ __forceinline__ u16 f2bf(float x){ __bf16 h=(__bf16)x; return __builtin_bit_cast(u16,h); }
__device__ __forceinline__ float bf2f(u16 u){ return (float)__builtin_bit_cast(__bf16,u); }

__global__ void k_scale(const float* __restrict__ raw, float* __restrict__ scale){
  int o = blockIdx.x*256 + threadIdx.x;
  if(o < ODIM){
    float x = raw[o];
    float k = (x > 20.f) ? x : log1pf(expf(x));
    scale[o] = k / (k + (float)(IDIM-1));
  }
}

__global__ void k_split(const f4* __restrict__ src, u16x4* __restrict__ hi,
                        u16x4* __restrict__ lo, int n4){
  int i = blockIdx.x*blockDim.x + threadIdx.x;
  int stride = gridDim.x*blockDim.x;
  for(; i<n4; i+=stride){
    f4 v = src[i];
    u16x4 h, l;
    #pragma unroll
    for(int j=0;j<4;++j){
      float x = v[j];
      u16 hb = f2bf(x);
      h[j] = hb;
      l[j] = f2bf(x - bf2f(hb));
    }
    hi[i]=h; lo[i]=l;
  }
}

__global__ void k_split_dir(const f4* __restrict__ src, const float* __restrict__ scale,
                            u16x4* __restrict__ hi, u16x4* __restrict__ lo, int n4){
  int i = blockIdx.x*blockDim.x + threadIdx.x;
  int stride = gridDim.x*blockDim.x;
  for(; i<n4; i+=stride){
    float s = scale[i>>10];
    f4 v = src[i];
    u16x4 h, l;
    #pragma unroll
    for(int j=0;j<4;++j){
      float x = v[j]*s;
      u16 hb = f2bf(x);
      h[j] = hb;
      l[j] = f2bf(x - bf2f(hb));
    }
    hi[i]=h; lo[i]=l;
  }
}

__device__ __forceinline__ void async16(const u16* g, u16* l){
  __builtin_amdgcn_global_load_lds((const __attribute__((address_space(1))) void*)g,
                                   (__attribute__((address_space(3))) void*)l, 16, 0, 0);
}

// LDS per buffer (u16 elems): Ah[256][32]@0, Al@8192, Rh[128][32]@16384,
// Rl@20480, Dh@24576, Dl@28672. Buffer stride 32768 elems (64 KB).
__global__ __launch_bounds__(512,2) void k_gemm(
    const u16* __restrict__ Ah, const u16* __restrict__ Al,
    const u16* __restrict__ Rh, const u16* __restrict__ Rl,
    const u16* __restrict__ Dh, const u16* __restrict__ Dl,
    const float* __restrict__ rad_b, const float* __restrict__ bias,
    float* __restrict__ out)
{
  __shared__ __align__(16) u16 smem[2*32768];   // 128 KB

  const int tid  = threadIdx.x;
  const int lane = tid & 63;
  const int wid  = tid >> 6;                    // 0..7
  const int wr = wid >> 1, wc = wid & 1;        // 4M x 2N wave grid

  // bijective XCD swizzle (1024 blocks % 8 == 0)
  const int bid = blockIdx.x;
  const int swz = (bid & 7)*128 + (bid >> 3);
  const int bm = swz >> 5;                      // 0..31  (256-row panels)
  const int bn = swz & 31;                      // 0..31  (128-col panels)

  // staging: LDS dest linear; GLOBAL fetch chunk XOR-swizzled (rule #21;
  // R2/R8-verified, 0 bank conflicts). (r0+128)>>1 keeps same XOR.
  const int r0   = tid >> 2;                    // 0..127
  const int cxor = (r0 >> 1) & 3;
  const int c0   = ((tid & 3) ^ cxor) * 8;
  const size_t arow = (size_t)(bm*BM + r0)*IDIM + c0;
  const size_t brow = (size_t)(bn*BN + r0)*IDIM + c0;
  const u16* gAh = Ah + arow;  const u16* gAl = Al + arow;
  const u16* gRh = Rh + brow;  const u16* gRl = Rl + brow;
  const u16* gDh = Dh + brow;  const u16* gDl = Dl + brow;
  u16* dst = smem + tid*8;

  // fragment reads (R2/R8-verified): XOR term = per-lane ((lane&15)>>1)&3
  const int lr   = lane & 15;
  const int koff = (((lane >> 4) ^ ((lr >> 1) & 3))) * 8;
  const int aoff = (wr*64 + lr)*BK + koff;
  const int boff = (wc*64 + lr)*BK + koff;

  f32x4 accR[4][4] = {};
  f32x4 accD[4][4] = {};

#define MFMA16(A,B,C) __builtin_amdgcn_mfma_f32_16x16x32_bf16(A,B,C,0,0,0)

#define STAGE_FULL(BUF, KT) { \
    const int _k = (KT)*BK; \
    u16* _df = dst + (BUF)*32768; \
    async16(gAh + _k,            _df);         \
    async16(gAh + 128*IDIM + _k, _df + 4096);  \
    async16(gAl + _k,            _df + 8192);  \
    async16(gAl + 128*IDIM + _k, _df + 12288); \
    async16(gRh + _k,            _df + 16384); \
    async16(gRl + _k,            _df + 20480); \
    async16(gDh + _k,            _df + 24576); \
    async16(gDl + _k,            _df + 28672); \
  }

// phase sync: barrier -> own-reads-done -> pinned -> prioritized MFMA
#define PH_PRE  __builtin_amdgcn_s_barrier(); \
    asm volatile("s_waitcnt lgkmcnt(0)" ::: "memory"); \
    __builtin_amdgcn_sched_barrier(0); \
    __builtin_amdgcn_s_setprio(1);
#define PH_POST __builtin_amdgcn_s_setprio(0); \
    __builtin_amdgcn_s_barrier(); \
    __builtin_amdgcn_sched_barrier(0);

// K-tile: 4 phases x 24 MFMA. Stage spread by region retirement:
// A in P2, R in P3, D after P4. vmcnt(VM) in P4 before its post-barrier.
#define K_TILE(BUF, VM, DOSTAGE, NEXTK) { \
    const u16* sb = smem + (BUF)*32768; \
    const int _ko = (NEXTK)*BK; \
    u16* _d = dst + (BUF)*32768; \
    bf16x8 ah[4], al[4]; \
    { /* P1: read A(8) + R ni01(4); MFMA accR ni01 */ \
      bf16x8 b0[2], b1[2]; \
      _Pragma("unroll") for(int mi=0;mi<4;++mi){ \
        ah[mi] = *(const bf16x8*)(sb +        aoff + mi*512); \
        al[mi] = *(const bf16x8*)(sb + 8192 + aoff + mi*512); } \
      _Pragma("unroll") for(int ni=0;ni<2;++ni){ \
        b0[ni] = *(const bf16x8*)(sb + 16384 + boff + ni*512); \
        b1[ni] = *(const bf16x8*)(sb + 20480 + boff + ni*512); } \
      PH_PRE \
      _Pragma("unroll") for(int mi=0;mi<4;++mi) \
        _Pragma("unroll") for(int ni=0;ni<2;++ni){ \
          accR[mi][ni] = MFMA16(ah[mi], b0[ni], accR[mi][ni]); \
          accR[mi][ni] = MFMA16(ah[mi], b1[ni], accR[mi][ni]); \
          accR[mi][ni] = MFMA16(al[mi], b0[ni], accR[mi][ni]); } \
      PH_POST \
    } \
    { /* P2: read R ni23(4); stage A of t+2 (A region retired in P1) */ \
      bf16x8 b0[2], b1[2]; \
      _Pragma("unroll") for(int ni=0;ni<2;++ni){ \
        b0[ni] = *(const bf16x8*)(sb + 16384 + boff + (ni+2)*512); \
        b1[ni] = *(const bf16x8*)(sb + 20480 + boff + (ni+2)*512); } \
      if (DOSTAGE) { \
        async16(gAh + _ko,            _d);         \
        async16(gAh + 128*IDIM + _ko, _d + 4096);  \
        async16(gAl + _ko,            _d + 8192);  \
        async16(gAl + 128*IDIM + _ko, _d + 12288); } \
      PH_PRE \
      _Pragma("unroll") for(int mi=0;mi<4;++mi) \
        _Pragma("unroll") for(int ni=0;ni<2;++ni){ \
          accR[mi][ni+2] = MFMA16(ah[mi], b0[ni], accR[mi][ni+2]); \
          accR[mi][ni+2] = MFMA16(ah[mi], b1[ni], accR[mi][ni+2]); \
          accR[mi][ni+2] = MFMA16(al[mi], b0[ni], accR[mi][ni+2]); } \
      PH_POST \
    } \
    { /* P3: read D ni01(4); stage R of t+2 (R region retired in P1+P2) */ \
      bf16x8 b0[2], b1[2]; \
      _Pragma("unroll") for(int ni=0;ni<2;++ni){ \
        b0[ni] = *(const bf16x8*)(sb + 24576 + boff + ni*512); \
        b1[ni] = *(const bf16x8*)(sb + 28672 + boff + ni*512); } \
      if (DOSTAGE) { \
        async16(gRh + _ko, _d + 16384); \
        async16(gRl + _ko, _d + 20480); } \
      PH_PRE \
      _Pragma("unroll") for(int mi=0;mi<4;++mi) \
        _Pragma("unroll") for(int ni=0;ni<2;++ni){ \
          accD[mi][ni] = MFMA16(ah[mi], b0[ni], accD[mi][ni]); \
          accD[mi][ni] = MFMA16(ah[mi], b1[ni], accD[mi][ni]); \
          accD[mi][ni] = MFMA16(al[mi], b0[ni], accD[mi][ni]); } \
      PH_POST \
    } \
    { /* P4: read D ni23(4); vmcnt(VM) before post-barrier; stage D after */ \
      bf16x8 b0[2], b1[2]; \
      _Pragma("unroll") for(int ni=0;ni<2;++ni){ \
        b0[ni] = *(const bf16x8*)(sb + 24576 + boff + (ni+2)*512); \
        b1[ni] = *(const bf16x8*)(sb + 28672 + boff + (ni+2)*512); } \
      PH_PRE \
      _Pragma("unroll") for(int mi=0;mi<4;++mi) \
        _Pragma("unroll") for(int ni=0;ni<2;++ni){ \
          accD[mi][ni+2] = MFMA16(ah[mi], b0[ni], accD[mi][ni+2]); \
          accD[mi][ni+2] = MFMA16(ah[mi], b1[ni], accD[mi][ni+2]); \
          accD[mi][ni+2] = MFMA16(al[mi], b0[ni], accD[mi][ni+2]); } \
      __builtin_amdgcn_s_setprio(0); \
      asm volatile("s_waitcnt vmcnt(" VM ")" ::: "memory"); \
      __builtin_amdgcn_s_barrier(); \
      __builtin_amdgcn_sched_barrier(0); \
      if (DOSTAGE) { \
        async16(gDh + _ko, _d + 24576); \
        async16(gDl + _ko, _d + 28672); } \
    } \
  }

  STAGE_FULL(0, 0)
  STAGE_FULL(1, 1)
  asm volatile("s_waitcnt vmcnt(8)" ::: "memory");   // tile0 landed; tile1 in flight
  __builtin_amdgcn_s_barrier();
  __builtin_amdgcn_sched_barrier(0);

  #pragma unroll 1
  for(int t=0; t<NKT-2; t+=2){          // tiles 0..125, staging 2..127
    K_TILE(0, "6", true, t+2)
    K_TILE(1, "6", true, t+3)
  }
  K_TILE(0, "0", false, 0)              // tile 126: drain t127 in P4
  K_TILE(1, "0", false, 0)              // tile 127

#undef K_TILE
#undef PH_PRE
#undef PH_POST
#undef STAGE_FULL
#undef MFMA16

  // epilogue: C/D layout col=lane&15, row=(lane>>4)*4+j (R2/R8-verified)
  const int orow0 = bm*BM + wr*64 + (lane>>4)*4;
  const int ocol0 = bn*BN + wc*64 + (lane & 15);
  #pragma unroll
  for(int ni=0;ni<4;++ni){
    const int col = ocol0 + ni*16;
    const float rb = rad_b[col];
    const float bs = bias[col];
    #pragma unroll
    for(int mi=0;mi<4;++mi){
      const int row = orow0 + mi*16;
      #pragma unroll
      for(int j=0;j<4;++j){
        float s  = accR[mi][ni][j] + rb;
        float sp = (s > 20.f) ? s : log1pf(expf(s));
        out[(size_t)(row+j)*ODIM + col] = accD[mi][ni][j]*sp + bs;
      }
    }
  }
}

extern "C" void kernel_launch(void* const* d_in, const int* in_sizes, int n_in,
                              void* d_out, int out_size, void* d_ws, size_t ws_size,
                              hipStream_t stream){
  (void)in_sizes; (void)n_in; (void)out_size; (void)ws_size;
  const float* inp  = (const float*)d_in[0];  // [8192,4096]
  const float* dirl = (const float*)d_in[1];  // [4096,4096]
  const float* draw = (const float*)d_in[2];  // [4096]
  const float* radw = (const float*)d_in[3];  // [4096,4096]
  const float* radb = (const float*)d_in[4];  // [4096]
  const float* bias = (const float*)d_in[5];  // [4096]
  float* out = (float*)d_out;

  char* ws = (char*)d_ws;
  u16* Ah = (u16*)(ws);
  u16* Al = (u16*)(ws +  67108864L);
  u16* Rh = (u16*)(ws + 134217728L);
  u16* Rl = (u16*)(ws + 167772160L);
  u16* Dh = (u16*)(ws + 201326592L);
  u16* Dl = (u16*)(ws + 234881024L);
  float* scale = (float*)(ws + 268435456L);

  k_scale<<<dim3(ODIM/256), dim3(256), 0, stream>>>(draw, scale);

  const int n4A = BDIM*IDIM/4;
  const int n4W = ODIM*IDIM/4;
  k_split<<<dim3(2048), dim3(256), 0, stream>>>((const f4*)inp,  (u16x4*)Ah, (u16x4*)Al, n4A);
  k_split<<<dim3(2048), dim3(256), 0, stream>>>((const f4*)radw, (u16x4*)Rh, (u16x4*)Rl, n4W);
  k_split_dir<<<dim3(2048), dim3(256), 0, stream>>>((const f4*)dirl, scale, (u16x4*)Dh, (u16x4*)Dl, n4W);

  k_gemm<<<dim3((BDIM/BM)*(ODIM/BN)), dim3(512), 0, stream>>>(
      Ah, Al, Rh, Rl, Dh, Dl, radb, bias, out);
}